// Round 5
// baseline (788.755 us; speedup 1.0000x reference)
//
#include <hip/hip_runtime.h>
#include <hip/hip_bf16.h>

#define BB 64
#define TT 1536
#define FF 512
#define TP 256
#define UU 256
#define GG 1024
#define NC 250

#define RV 42            // R quads in VGPRs
#define RLN 12           // R quads in LDS  (42..53)
#define RST 10           // R quads streamed from L2 (54..63)

typedef _Float16 h2_t __attribute__((ext_vector_type(2)));
typedef _Float16 f16x8 __attribute__((ext_vector_type(8)));
typedef float f32x4 __attribute__((ext_vector_type(4)));

#if defined(__has_builtin)
#  if __has_builtin(__builtin_amdgcn_fdot2)
#    define FDOT2(a, b, c) __builtin_amdgcn_fdot2((a), (b), (c), false)
#  endif
#endif
#ifndef FDOT2
__device__ __forceinline__ float fdot2_fb(h2_t a, h2_t b, float c) {
    return c + (float)a[0] * (float)b[0] + (float)a[1] * (float)b[1];
}
#  define FDOT2(a, b, c) fdot2_fb((a), (b), (c))
#endif

#define BC(u) __builtin_bit_cast(h2_t, (u))

__device__ __forceinline__ float hsig(float z) {
    return fminf(fmaxf(fmaf(z, 0.2f, 0.5f), 0.0f), 1.0f);
}

__device__ __forceinline__ float ftanh(float x) {
    float ax = fabsf(x);
    float e = __expf(-2.0f * ax);
    float t = (1.0f - e) / (1.0f + e);
    return copysignf(t, x);
}

__device__ __forceinline__ void dot4(float& z, const uint4& r, const uint4& h) {
    z = FDOT2(BC(r.x), BC(h.x), z);
    z = FDOT2(BC(r.y), BC(h.y), z);
    z = FDOT2(BC(r.z), BC(h.z), z);
    z = FDOT2(BC(r.w), BC(h.w), z);
}

// quad all-reduce add via DPP quad_perm (VALU pipe, no LDS)
#if defined(__has_builtin) && __has_builtin(__builtin_amdgcn_mov_dpp)
template <int CTRL>
__device__ __forceinline__ float qperm(float v) {
    return __builtin_bit_cast(float,
        __builtin_amdgcn_mov_dpp(__builtin_bit_cast(int, v), CTRL, 0xf, 0xf, true));
}
#else
template <int CTRL>
__device__ __forceinline__ float qperm(float v) {
    return __shfl_xor(v, CTRL == 0xB1 ? 1 : 2, 64);
}
#endif

// ---------------------------------------------------------------------------
// Kernel 1: AveragePooling1D(6).  x[64,1536,512] f32 -> xph[64,256,512] f16
// ---------------------------------------------------------------------------
__global__ __launch_bounds__(256) void pool_kernel(const float* __restrict__ x,
                                                   _Float16* __restrict__ xph) {
    int idx = blockIdx.x * 256 + threadIdx.x;
    int f = idx & (FF - 1);
    int m = idx >> 9;
    int b = m >> 8;
    int tp = m & (TP - 1);
    const float* src = x + ((size_t)b * TT + (size_t)tp * 6) * FF + f;
    float s = 0.0f;
#pragma unroll
    for (int j = 0; j < 6; ++j) s += src[j * FF];
    xph[idx] = (_Float16)(s * (1.0f / 6.0f));
}

// ---------------------------------------------------------------------------
// Kernel 2a: W f32 [512,1024] -> Wt f16 [1024,512] (transposed for MFMA B)
// ---------------------------------------------------------------------------
__global__ __launch_bounds__(256) void conv_wt(const float* __restrict__ W,
                                               _Float16* __restrict__ Wt) {
    int d = blockIdx.x * 256 + threadIdx.x;
    int n = d >> 9;
    int k = d & 511;
    Wt[d] = (_Float16)W[(size_t)k * GG + n];
}

// ---------------------------------------------------------------------------
// Kernel 2b: R f32 [256,1024] -> Rq packed f16, quad-ownership layout.
// Thread t = 4*jq + s owns units {2jq, 2jq+1} x 4 gates, K-slice s (64 k).
// uint4 Rq[q][t], q = cc*8 + p4, cc = 2*g3 + uo:
//   col = 256*g3 + 2*jq + uo;  dword i packs k = 64s + 8*p4 + 2i, +1.
// ---------------------------------------------------------------------------
__global__ __launch_bounds__(256) void conv_rq(const float* __restrict__ R,
                                               unsigned* __restrict__ Rq) {
    int d = blockIdx.x * 256 + threadIdx.x;   // [0, 131072)
    int i = d & 3;
    int qt = d >> 2;
    int t = qt & 511;
    int q = qt >> 9;
    int s = t & 3, jq = t >> 2;
    int cc = q >> 3, p4 = q & 7;
    int g3 = cc >> 1, uo = cc & 1;
    int col = 256 * g3 + 2 * jq + uo;
    int k = 64 * s + 8 * p4 + 2 * i;
    h2_t p;
    p[0] = (_Float16)R[(size_t)k * GG + col];
    p[1] = (_Float16)R[(size_t)(k + 1) * GG + col];
    Rq[d] = __builtin_bit_cast(unsigned, p);
}

// ---------------------------------------------------------------------------
// Kernel 3: zx = xph @ W + b via f16 MFMA 16x16x32 (unchanged).
// ---------------------------------------------------------------------------
__global__ __launch_bounds__(256, 2) void gemm_zx_mfma(const _Float16* __restrict__ Ah,
                                                       const _Float16* __restrict__ Bt,
                                                       const float* __restrict__ bias,
                                                       float* __restrict__ C) {
    __shared__ _Float16 As[128 * 40];
    __shared__ _Float16 Bs[128 * 40];
    const int tid = threadIdx.x;
    const int bn = blockIdx.x * 128;
    const int bm = blockIdx.y * 128;
    const int wave = tid >> 6, lane = tid & 63;
    const int wm = (wave & 1) * 64, wn = (wave >> 1) * 64;
    const int l15 = lane & 15, q8 = (lane >> 4) * 8;
    const int srow = tid >> 1, shalf = tid & 1;

    f32x4 acc[4][4] = {};
    const uint4* ag = (const uint4*)(Ah + (size_t)(bm + srow) * FF);
    const uint4* bg = (const uint4*)(Bt + (size_t)(bn + srow) * FF);
    uint4* as_st = (uint4*)As + 5 * srow + 2 * shalf;
    uint4* bs_st = (uint4*)Bs + 5 * srow + 2 * shalf;

    for (int k0 = 0; k0 < FF; k0 += 32) {
        int qi = (k0 >> 3) + shalf * 2;
        uint4 a0 = ag[qi], a1 = ag[qi + 1];
        uint4 b0 = bg[qi], b1 = bg[qi + 1];
        __syncthreads();
        as_st[0] = a0; as_st[1] = a1;
        bs_st[0] = b0; bs_st[1] = b1;
        __syncthreads();
        f16x8 af[4], bf[4];
#pragma unroll
        for (int mt = 0; mt < 4; ++mt)
            af[mt] = *(const f16x8*)&As[(wm + 16 * mt + l15) * 40 + q8];
#pragma unroll
        for (int nt = 0; nt < 4; ++nt)
            bf[nt] = *(const f16x8*)&Bs[(wn + 16 * nt + l15) * 40 + q8];
#pragma unroll
        for (int mt = 0; mt < 4; ++mt)
#pragma unroll
            for (int nt = 0; nt < 4; ++nt)
                acc[mt][nt] = __builtin_amdgcn_mfma_f32_16x16x32_f16(af[mt], bf[nt],
                                                                    acc[mt][nt], 0, 0, 0);
    }
    const int rq = (lane >> 4) * 4;
#pragma unroll
    for (int nt = 0; nt < 4; ++nt) {
        int col = bn + wn + 16 * nt + l15;
        float bv = bias[col];
#pragma unroll
        for (int mt = 0; mt < 4; ++mt) {
#pragma unroll
            for (int r = 0; r < 4; ++r) {
                int row = bm + wm + 16 * mt + rq + r;
                C[(size_t)row * GG + col] = ((const float*)&acc[mt][nt])[r] + bv;
            }
        }
    }
}

// ---------------------------------------------------------------------------
// Kernel 4: LSTM scan. 64 WGs x 512 thr. Quad jq owns units {2jq,2jq+1} x 4
// gates; lane s=t&3 owns K-slice [64s,64s+64). DPP butterfly -> lanes s<2
// compute gates in-quad (no z exchange). h double-buffered in LDS, ONE
// barrier/step. R tiers: rv[42] VGPR + Rl[12] LDS (96KB) + 10 streamed L2.
// FIX vs R4: h write base is nb*8 f16 (uint4 idx -> 8 f16), was 2*nb*8 (OOB
// for buffer 1 -> odd steps read h=0).
// ---------------------------------------------------------------------------
__global__ __launch_bounds__(512, 2) void lstm_scan(const float* __restrict__ zx,
                                                    const uint4* __restrict__ Rq4,
                                                    float* __restrict__ hfin) {
    __shared__ uint4 Rl[RLN][512];                   // 98304 B
    __shared__ __align__(16) uint4 h2s[2 * 36];      // 2 bufs * 4 slices * 9 uint4
    const int b = blockIdx.x;
    const int t = threadIdx.x;
    const int s = t & 3, jq = t >> 2;

    uint4 rv[RV];
#pragma unroll
    for (int q = 0; q < RV; ++q) rv[q] = Rq4[q * 512 + t];
#pragma unroll
    for (int j = 0; j < RLN; ++j) Rl[j][t] = Rq4[(RV + j) * 512 + t];
    if (t < 288) ((unsigned*)h2s)[t] = 0u;
    float c = 0.0f;
    const float* zrow = zx + (size_t)b * TP * GG;
    const uint4* sRq = Rq4 + (RV + RLN) * 512 + t;
    const uint4* h4 = h2s;
    __syncthreads();

    for (int step = 0; step < TP; ++step) {
        const int hb = (step & 1) * 36;          // read buffer (uint4 idx)
        const int nb = 36 - hb;                  // write buffer (uint4 idx)
        // prefetch streamed R and this step's zx gate values
        uint4 st[RST];
#pragma unroll
        for (int j = 0; j < RST; ++j) st[j] = sRq[j * 512];
        float zv0 = 0.f, zv1 = 0.f, zv2 = 0.f, zv3 = 0.f;
        if (s < 2) {
            const float* zr = zrow + (size_t)step * GG + 2 * jq + s;
            zv0 = zr[0]; zv1 = zr[UU]; zv2 = zr[2 * UU]; zv3 = zr[3 * UU];
        }

        float z[8] = {};
#pragma unroll
        for (int p4 = 0; p4 < 8; ++p4) {
            uint4 hh = h4[hb + 9 * s + p4];
#pragma unroll
            for (int cc = 0; cc < 8; ++cc) {
                int q = cc * 8 + p4;
                if (q < RV)            dot4(z[cc], rv[q], hh);
                else if (q < RV + RLN) dot4(z[cc], Rl[q - RV][t], hh);
                else                   dot4(z[cc], st[q - RV - RLN], hh);
            }
        }
        // quad butterfly all-reduce over K-slices
#pragma unroll
        for (int cc = 0; cc < 8; ++cc) {
            z[cc] += qperm<0xB1>(z[cc]);   // xor 1
            z[cc] += qperm<0x4E>(z[cc]);   // xor 2
        }
        if (s < 2) {
            float zi = z[0 + s] + zv0;
            float zf = z[2 + s] + zv1;
            float zg = z[4 + s] + zv2;
            float zo = z[6 + s] + zv3;
            float ig = hsig(zi);
            float fg = hsig(zf);
            float gv = ftanh(zg);
            float og = hsig(zo);
            c = fmaf(fg, c, ig * gv);
            float h = og * ftanh(c);
            int u = 2 * jq + s;
            ((_Float16*)h2s)[nb * 8 + (u >> 6) * 72 + (u & 63)] = (_Float16)h;
            if (step == TP - 1) hfin[(size_t)b * UU + u] = h;
        }
        __syncthreads();
    }
}

// ---------------------------------------------------------------------------
// Kernel 5: logits = h @ Wd + bd; softmax.  One WG per batch row.
// ---------------------------------------------------------------------------
__global__ __launch_bounds__(256) void dense_softmax(const float* __restrict__ hfin,
                                                     const float* __restrict__ Wd,
                                                     const float* __restrict__ bd,
                                                     float* __restrict__ out) {
    __shared__ __align__(16) float hbuf[UU];
    __shared__ float red[256];
    const int b = blockIdx.x;
    const int tid = threadIdx.x;
    hbuf[tid] = hfin[(size_t)b * UU + tid];
    __syncthreads();
    float logit = -3.0e38f;
    if (tid < NC) {
        float acc = bd[tid];
        for (int u = 0; u < UU; u += 4) {
            float4 hv = *(const float4*)&hbuf[u];
            acc = fmaf(hv.x, Wd[(size_t)(u + 0) * NC + tid], acc);
            acc = fmaf(hv.y, Wd[(size_t)(u + 1) * NC + tid], acc);
            acc = fmaf(hv.z, Wd[(size_t)(u + 2) * NC + tid], acc);
            acc = fmaf(hv.w, Wd[(size_t)(u + 3) * NC + tid], acc);
        }
        logit = acc;
    }
    red[tid] = logit;
    __syncthreads();
    for (int sft = 128; sft > 0; sft >>= 1) {
        if (tid < sft) red[tid] = fmaxf(red[tid], red[tid + sft]);
        __syncthreads();
    }
    float mx = red[0];
    __syncthreads();
    float e = (tid < NC) ? expf(logit - mx) : 0.0f;
    red[tid] = e;
    __syncthreads();
    for (int sft = 128; sft > 0; sft >>= 1) {
        if (tid < sft) red[tid] += red[tid + sft];
        __syncthreads();
    }
    if (tid < NC) out[(size_t)b * NC + tid] = e / red[0];
}

// ---------------------------------------------------------------------------
extern "C" void kernel_launch(void* const* d_in, const int* in_sizes, int n_in,
                              void* d_out, int out_size, void* d_ws, size_t ws_size,
                              hipStream_t stream) {
    const float* x  = (const float*)d_in[0];
    const float* W  = (const float*)d_in[1];
    const float* R  = (const float*)d_in[2];
    const float* bv = (const float*)d_in[3];
    const float* Wd = (const float*)d_in[4];
    const float* bd = (const float*)d_in[5];
    float* out = (float*)d_out;

    char* ws = (char*)d_ws;
    _Float16* xph = (_Float16*)ws;                         // 16 MB
    float* zx = (float*)(ws + 16777216);                   // 64 MB
    _Float16* Wt = (_Float16*)(ws + 83886080);             // 1 MB
    unsigned* Rq = (unsigned*)(ws + 84934656);             // 512 KB
    float* hfin = (float*)(ws + 85458944);                 // 64 KB

    hipLaunchKernelGGL(pool_kernel, dim3(32768), dim3(256), 0, stream, x, xph);
    hipLaunchKernelGGL(conv_wt, dim3(2048), dim3(256), 0, stream, W, Wt);
    hipLaunchKernelGGL(conv_rq, dim3(512), dim3(256), 0, stream, R, Rq);
    hipLaunchKernelGGL(gemm_zx_mfma, dim3(8, 128), dim3(256), 0, stream,
                       xph, Wt, bv, zx);
    hipLaunchKernelGGL(lstm_scan, dim3(64), dim3(512), 0, stream, zx,
                       (const uint4*)Rq, hfin);
    hipLaunchKernelGGL(dense_softmax, dim3(64), dim3(256), 0, stream, hfin, Wd, bd, out);
}